// Round 1
// 1622.119 us; speedup vs baseline: 1.1679x; 1.1679x over previous
//
#include <hip/hip_runtime.h>

#define T_STEPS 512
#define INPUT   13
#define HIDDEN  64
#define NGATES  256   // 4*HIDDEN
#define MB      4     // batch rows per block (was 8): grid 1024 -> 4 blocks/CU
#define CS      16    // timesteps per x-chunk
#define XPAD    16    // padded input dim (13 -> 16)
#define NCHUNK  (T_STEPS / CS)

__device__ __forceinline__ float sigmoid_f(float x) {
    return 1.0f / (1.0f + __expf(-x));
}
__device__ __forceinline__ float tanh_f(float x) {
    // tanh(x) = 1 - 2/(1+exp(2x)); saturates correctly for large |x|
    return 1.0f - 2.0f / (1.0f + __expf(2.0f * x));
}

// waves_per_eu(4,4): pin allocator to exactly 4 waves/EU -> 128-VGPR budget.
// min alone lets the allocator squeeze registers toward 8 waves/EU and spill
// the loop-invariant weight arrays (prev kernel: VGPR_Count=76 < the ~100
// needed for resident wh[64]+wi[13]). max=4 stops the squeeze.
__global__
__launch_bounds__(256)
__attribute__((amdgpu_waves_per_eu(4, 4)))
void lstm_fused_kernel(const float* __restrict__ x,
                       const float* __restrict__ W_ih,
                       const float* __restrict__ W_hh,
                       const float* __restrict__ b_ih,
                       const float* __restrict__ b_hh,
                       const float* __restrict__ W_fc,
                       const float* __restrict__ b_fc,
                       float* __restrict__ out)
{
    __shared__ float xs[2][MB][CS][XPAD];   // 8 KB: double-buffered x chunks
    __shared__ float hl[MB][HIDDEN];        // 1 KB: hidden state
    __shared__ float gl[MB][NGATES];        // 4 KB: gate pre-activations

    const int tid  = threadIdx.x;
    const int row0 = blockIdx.x * MB;

    // ---- per-thread weights: this thread owns gate g = tid ----
    float wi[INPUT];
    #pragma unroll
    for (int i = 0; i < INPUT; ++i)
        wi[i] = W_ih[tid * INPUT + i];

    float wh[HIDDEN];
    #pragma unroll
    for (int j = 0; j < HIDDEN; ++j)
        wh[j] = W_hh[tid * HIDDEN + j];

    const float bias = b_ih[tid] + b_hh[tid];

    // ---- init h (LDS, exactly one element per thread) and c (reg) ----
    hl[tid >> 6][tid & 63] = 0.0f;
    float c0 = 0.0f;

    // ---- x chunk loader: [MB][CS][XPAD] = 1024 floats, 4 elems/thread ----
    float stg[4];
    auto load_chunk = [&](int c) {
        #pragma unroll
        for (int k = 0; k < 4; ++k) {
            int idx = tid + k * 256;        // 0..1023
            int r   = idx >> 8;             // /(CS*XPAD)
            int rem = idx & 255;
            int tt  = rem >> 4;
            int i   = rem & 15;
            float v = 0.0f;
            if (i < INPUT)
                v = x[(size_t)(row0 + r) * (T_STEPS * INPUT)
                      + (size_t)(c * CS + tt) * INPUT + i];
            stg[k] = v;
        }
    };
    auto store_chunk = [&](int buf) {
        #pragma unroll
        for (int k = 0; k < 4; ++k) {
            int idx = tid + k * 256;
            ((float*)xs[buf])[idx] = stg[k];
        }
    };

    load_chunk(0);
    store_chunk(0);
    __syncthreads();

    for (int cidx = 0; cidx < NCHUNK; ++cidx) {
        const int cur = cidx & 1;
        if (cidx + 1 < NCHUNK)
            load_chunk(cidx + 1);   // issue early; consumed after step loop

        #pragma unroll 1
        for (int tt = 0; tt < CS; ++tt) {
            // ---- gates: acc[r] = bias + x.Wih_row + h.Whh_row ----
            float acc[MB];
            #pragma unroll
            for (int r = 0; r < MB; ++r) acc[r] = bias;

            // x part: 13 real inputs = 3 float4 + 1 scalar per row
            #pragma unroll
            for (int q = 0; q < 3; ++q) {
                #pragma unroll
                for (int r = 0; r < MB; ++r) {
                    const float4 xv = *(const float4*)&xs[cur][r][tt][q * 4];
                    acc[r] = fmaf(xv.x, wi[q * 4 + 0], acc[r]);
                    acc[r] = fmaf(xv.y, wi[q * 4 + 1], acc[r]);
                    acc[r] = fmaf(xv.z, wi[q * 4 + 2], acc[r]);
                    acc[r] = fmaf(xv.w, wi[q * 4 + 3], acc[r]);
                }
            }
            #pragma unroll
            for (int r = 0; r < MB; ++r)
                acc[r] = fmaf(xs[cur][r][tt][12], wi[12], acc[r]);

            // h part: 16 float4 per row
            #pragma unroll
            for (int q = 0; q < HIDDEN / 4; ++q) {
                #pragma unroll
                for (int r = 0; r < MB; ++r) {
                    const float4 hv = *(const float4*)&hl[r][q * 4];
                    acc[r] = fmaf(hv.x, wh[q * 4 + 0], acc[r]);
                    acc[r] = fmaf(hv.y, wh[q * 4 + 1], acc[r]);
                    acc[r] = fmaf(hv.z, wh[q * 4 + 2], acc[r]);
                    acc[r] = fmaf(hv.w, wh[q * 4 + 3], acc[r]);
                }
            }
            #pragma unroll
            for (int r = 0; r < MB; ++r)
                gl[r][tid] = acc[r];
            __syncthreads();

            // ---- cell update: this thread owns cell (r = tid>>6, k = tid&63) ----
            {
                const int k = tid & 63;
                const int r = tid >> 6;          // 0..3
                float ig = sigmoid_f(gl[r][k]);
                float fg = sigmoid_f(gl[r][64 + k]);
                float gg = tanh_f   (gl[r][128 + k]);
                float og = sigmoid_f(gl[r][192 + k]);
                c0 = fg * c0 + ig * gg;
                hl[r][k] = og * tanh_f(c0);
            }
            __syncthreads();
        }

        if (cidx + 1 < NCHUNK) {
            store_chunk(1 - cur);   // waits on the global loads issued above
            __syncthreads();
        }
    }

    // ---- epilogue: out[row] = sigmoid(h_T . W_fc + b_fc) ----
    if (tid < MB) {
        float acc = b_fc[0];
        #pragma unroll
        for (int j = 0; j < HIDDEN; ++j)
            acc = fmaf(hl[tid][j], W_fc[j], acc);
        out[row0 + tid] = sigmoid_f(acc);
    }
}

extern "C" void kernel_launch(void* const* d_in, const int* in_sizes, int n_in,
                              void* d_out, int out_size, void* d_ws, size_t ws_size,
                              hipStream_t stream) {
    const float* x    = (const float*)d_in[0];
    const float* W_ih = (const float*)d_in[1];
    const float* W_hh = (const float*)d_in[2];
    const float* b_ih = (const float*)d_in[3];
    const float* b_hh = (const float*)d_in[4];
    const float* W_fc = (const float*)d_in[5];
    const float* b_fc = (const float*)d_in[6];
    float* out = (float*)d_out;

    const int B = 4096;
    dim3 grid(B / MB), block(256);
    lstm_fused_kernel<<<grid, block, 0, stream>>>(x, W_ih, W_hh, b_ih, b_hh,
                                                  W_fc, b_fc, out);
}